// Round 1
// 257.985 us; speedup vs baseline: 1.0040x; 1.0040x over previous
//
#include <hip/hip_runtime.h>
#include <hip/hip_fp16.h>
#include <math.h>

#define N_NODES 100000
#define N_EDGES 1600000
#define RR      6
#define CIN     8
#define COUT    16
#define EPS     1e-8f

#define NBLK_A  512
#define ABLOCK  1024                    // was 512: grid of 512 blocks only gave
                                        // 2 blocks/CU = 16 waves; 1024-thr blocks
                                        // give 32 waves/CU with identical memory
                                        // pattern (same CHUNK, same runs)
#define CHUNK   (N_EDGES / NBLK_A)      // 3125 (exact)
#define NBUCK   391                     // dst >> 8
#define RECCAP  4608                    // per-bucket cap (mean 4096, +8 sigma)
#define QCAP    1536                    // per-quarter cap

// float pair -> packed fp16x2 (RNE)
__device__ inline unsigned int pack_f16(float a, float b) {
    __half2 h = __floats2half2_rn(a, b);
    return *(unsigned int*)&h;
}

// ---------------------------------------------------------------------------
// Phase A: per-chunk LDS counting sort by bucket; emit header (4B) and
// fp16 payload (24B) streams in bucket-sorted runs with plain stores.
// ---------------------------------------------------------------------------
__global__ __launch_bounds__(ABLOCK)
void partition_kernel(const int* __restrict__ edges,
                      const float* __restrict__ sten,
                      int* __restrict__ gcur,
                      unsigned int* __restrict__ hdr,
                      unsigned int* __restrict__ pay) {
    __shared__ int cnt[NBUCK], cur[NBUCK], base[NBUCK], gbase[NBUCK];
    __shared__ unsigned int sorted[CHUNK];

    int tid = threadIdx.x;
    int blk = blockIdx.x;
    int e0 = blk * CHUNK;

    for (int i = tid; i < NBUCK; i += ABLOCK) { cnt[i] = 0; cur[i] = 0; }
    __syncthreads();

    // pass 1: count buckets
    for (int i = tid; i < CHUNK; i += ABLOCK) {
        int2 ed = ((const int2*)edges)[e0 + i];
        atomicAdd(&cnt[ed.y >> 8], 1);
    }
    __syncthreads();

    // exclusive scan cnt -> base (wave 0)
    if (tid < 64) {
        int lane = tid;
        int off = 0;
        for (int c = 0; c < NBUCK; c += 64) {
            int idx = c + lane;
            int v = (idx < NBUCK) ? cnt[idx] : 0;
            int orig = v;
#pragma unroll
            for (int d = 1; d < 64; d <<= 1) {
                int t = __shfl_up(v, d);
                if (lane >= d) v += t;
            }
            if (idx < NBUCK) base[idx] = off + v - orig;
            off += __shfl(v, 63);
        }
    }
    __syncthreads();

    // reserve global run per bucket
    for (int b = tid; b < NBUCK; b += ABLOCK) {
        int c = cnt[b];
        gbase[b] = (c > 0) ? atomicAdd(&gcur[b], c) : 0;
    }
    __syncthreads();

    // pass 2: build sorted order (pos -> (i<<9)|b)
    for (int i = tid; i < CHUNK; i += ABLOCK) {
        int2 ed = ((const int2*)edges)[e0 + i];
        int b = ed.y >> 8;
        int p = base[b] + atomicAdd(&cur[b], 1);
        sorted[p] = ((unsigned int)i << 9) | (unsigned int)b;
    }
    __syncthreads();

    // pass 3: emit both streams in sorted order (sequential run writes)
    for (int p = tid; p < CHUNK; p += ABLOCK) {
        unsigned int v = sorted[p];
        int b = (int)(v & 511u);
        int i = (int)(v >> 9);
        int e = e0 + i;
        long long slot = (long long)gbase[b] + (p - base[b]);
        if (slot < RECCAP) {
            int2 ed = ((const int2*)edges)[e];          // L1/L2 hit
            size_t rs = (size_t)b * RECCAP + slot;
            hdr[rs] = ((unsigned int)ed.x << 8) | (unsigned int)(ed.y & 255);
            const float4* sp = (const float4*)(sten + (size_t)e * 12);  // L2 (chunk slice)
            float4 s0 = sp[0], s1 = sp[1], s2 = sp[2];
            uint2 w01 = { pack_f16(s0.x, s0.y), pack_f16(s0.z, s0.w) };
            uint2 w23 = { pack_f16(s1.x, s1.y), pack_f16(s1.z, s1.w) };
            uint2 w45 = { pack_f16(s2.x, s2.y), pack_f16(s2.z, s2.w) };
            unsigned int* dp = pay + rs * 6;            // 24B stride, 8B-aligned
            *(uint2*)(dp + 0) = w01;
            *(uint2*)(dp + 2) = w23;
            *(uint2*)(dp + 4) = w45;
        }
    }
}

// ---------------------------------------------------------------------------
// Phase B: 4 blocks per bucket (quarter = 64 nodes). Dense header read ->
// LDS node-sort (packed src|j, no hdrs[] LDS mirror) -> 64 nodes x 4 lanes,
// fp16 payload decode at consume.
// LDS: idxs 6KB + fre/fim 6KB + counters ~0.9KB = ~13KB (was 28.4KB with
// hdrs[RECCAP]); header slice (16KB) is L1-resident for the second pass.
// ---------------------------------------------------------------------------
__global__ __launch_bounds__(256, 6)
void bucket_kernel(const float* __restrict__ x,
                   const float* __restrict__ weight,
                   const float* __restrict__ offset,
                   const float* __restrict__ bias,
                   const int* __restrict__ gcur,
                   const unsigned int* __restrict__ hdr,
                   const unsigned int* __restrict__ pay,
                   float* __restrict__ out) {
    __shared__ unsigned int idxs[QCAP];         // 6 KB: (src<<13) | j
    __shared__ int cnt[64], nbase[64], cur2[64];
    __shared__ float fre[RR * CIN * COUT];
    __shared__ float fim[RR * CIN * COUT];
    __shared__ float bsh[COUT];

    int tid = threadIdx.x;
    int b   = blockIdx.x >> 2;
    int q   = blockIdx.x & 3;

    for (int i = tid; i < RR * CIN * COUT; i += 256) {
        int co = i % (CIN * COUT);              // offset is (CIN, COUT)
        float w = weight[i], off = offset[co];
        fre[i] = w * cosf(off);
        fim[i] = w * sinf(off);
    }
    if (tid < COUT) bsh[tid] = bias[tid];
    if (tid < 64) { cnt[tid] = 0; cur2[tid] = 0; }
    __syncthreads();

    int T = gcur[b];
    if (T > RECCAP) T = RECCAP;

    const unsigned int* hslice = hdr + (size_t)b * RECCAP;

    // pass 1: dense, coalesced header read; count this quarter's nodes
    for (int j = tid; j < T; j += 256) {
        unsigned int h = hslice[j];
        int d = (int)(h & 255u);
        if ((d >> 6) == q) atomicAdd(&cnt[d & 63], 1);
    }
    __syncthreads();

    // exclusive scan of 64 counters (wave 0)
    if (tid < 64) {
        int v = cnt[tid];
        int orig = v;
#pragma unroll
        for (int d = 1; d < 64; d <<= 1) {
            int t = __shfl_up(v, d);
            if (tid >= d) v += t;
        }
        nbase[tid] = v - orig;
    }
    __syncthreads();

    // pass 2: re-read headers (L1-hot, 16KB slice); place packed (src<<13)|j
    for (int j = tid; j < T; j += 256) {
        unsigned int h = hslice[j];
        int d = (int)(h & 255u);
        if ((d >> 6) == q) {
            int dl = d & 63;
            int pos = nbase[dl] + atomicAdd(&cur2[dl], 1);
            if (pos < QCAP)
                idxs[pos] = ((h >> 8) << 13) | (unsigned int)j;
        }
    }
    __syncthreads();

    // compute: 64 nodes x 4 lanes (single batch)
    int local = tid >> 2;
    int n = b * 256 + q * 64 + local;
    int l = tid & 3;
    if (n >= N_NODES) return;

    int deg  = cnt[local];
    int base = nbase[local];
    if (base + deg > QCAP) deg = (base < QCAP) ? (QCAP - base) : 0;

    float ar[RR][2] = {};
    float ai[RR][2] = {};

    uint2 p0 = {}, p1 = {}, p2 = {};
    float2 xv = {};
    if (deg > 0) {
        unsigned int pk = idxs[base];
        int j   = (int)(pk & 8191u);
        int src = (int)(pk >> 13);
        const unsigned int* pp = pay + ((size_t)b * RECCAP + j) * 6;
        p0 = *(const uint2*)(pp + 0);
        p1 = *(const uint2*)(pp + 2);
        p2 = *(const uint2*)(pp + 4);
        xv = *(const float2*)(x + (size_t)src * CIN + 2 * l);
    }
    for (int k = 0; k < deg; ++k) {
        uint2 q0 = {}, q1 = {}, q2 = {};
        float2 nx = {};
        if (k + 1 < deg) {
            unsigned int pk = idxs[base + k + 1];
            int j   = (int)(pk & 8191u);
            int src = (int)(pk >> 13);
            const unsigned int* pp = pay + ((size_t)b * RECCAP + j) * 6;
            q0 = *(const uint2*)(pp + 0);
            q1 = *(const uint2*)(pp + 2);
            q2 = *(const uint2*)(pp + 4);
            nx = *(const float2*)(x + (size_t)src * CIN + 2 * l);
        }
        unsigned int wv[6] = {p0.x, p0.y, p1.x, p1.y, p2.x, p2.y};
#pragma unroll
        for (int r = 0; r < RR; ++r) {
            __half2 h = *(__half2*)&wv[r];
            float sre = __half2float(__low2half(h));
            float sim = __half2float(__high2half(h));
            ar[r][0] = fmaf(sre, xv.x, ar[r][0]);
            ar[r][1] = fmaf(sre, xv.y, ar[r][1]);
            ai[r][0] = fmaf(sim, xv.x, ai[r][0]);
            ai[r][1] = fmaf(sim, xv.y, ai[r][1]);
        }
        p0 = q0; p1 = q1; p2 = q2; xv = nx;
    }

    float yr[COUT], yi[COUT];
#pragma unroll
    for (int o = 0; o < COUT; ++o) { yr[o] = 0.f; yi[o] = 0.f; }
#pragma unroll
    for (int r = 0; r < RR; ++r) {
#pragma unroll
        for (int j = 0; j < 2; ++j) {
            int c = 2 * l + j;
            float are = ar[r][j], aim = ai[r][j];
            const float* fr = &fre[(r * CIN + c) * COUT];
            const float* fi = &fim[(r * CIN + c) * COUT];
#pragma unroll
            for (int o = 0; o < COUT; ++o) {
                yr[o] = fmaf(are, fr[o], yr[o]);
                yr[o] = fmaf(-aim, fi[o], yr[o]);
                yi[o] = fmaf(are, fi[o], yi[o]);
                yi[o] = fmaf(aim, fr[o], yi[o]);
            }
        }
    }
#pragma unroll
    for (int o = 0; o < COUT; ++o) {
        yr[o] += __shfl_xor(yr[o], 1);
        yr[o] += __shfl_xor(yr[o], 2);
        yi[o] += __shfl_xor(yi[o], 1);
        yi[o] += __shfl_xor(yi[o], 2);
    }
    float tmp[8];
    int ob = 4 * l;
#pragma unroll
    for (int j = 0; j < 4; ++j) {
        int o = ob + j;
        float re = yr[o], im = yi[o];
        float mag = sqrtf(re * re + im * im);
        float sc = fmaxf(mag + bsh[o], 0.f) / (mag + EPS);
        tmp[2 * j]     = re * sc;
        tmp[2 * j + 1] = im * sc;
    }
    float4* op = (float4*)(out + (size_t)n * 2 * COUT + 8 * l);
    op[0] = ((const float4*)tmp)[0];
    op[1] = ((const float4*)tmp)[1];
}

extern "C" void kernel_launch(void* const* d_in, const int* in_sizes, int n_in,
                              void* d_out, int out_size, void* d_ws, size_t ws_size,
                              hipStream_t stream) {
    const float* x      = (const float*)d_in[0];
    const int*   edges  = (const int*)d_in[1];
    const float* sten   = (const float*)d_in[2];
    const float* weight = (const float*)d_in[3];
    const float* offset = (const float*)d_in[4];
    const float* bias   = (const float*)d_in[5];
    float* out = (float*)d_out;

    // ws: gcur (4 KB) | hdr (NBUCK*RECCAP*4B = 7.2 MB) | pay (NBUCK*RECCAP*24B = 43.2 MB)
    int* gcur = (int*)d_ws;
    unsigned int* hdr = (unsigned int*)((char*)d_ws + 4096);
    unsigned int* pay = hdr + (size_t)NBUCK * RECCAP;

    (void)hipMemsetAsync(gcur, 0, sizeof(int) * NBUCK, stream);

    partition_kernel<<<NBLK_A, ABLOCK, 0, stream>>>(edges, sten, gcur, hdr, pay);
    bucket_kernel<<<NBUCK * 4, 256, 0, stream>>>(x, weight, offset, bias,
                                                 gcur, hdr, pay, out);
}

// Round 2
// 222.010 us; speedup vs baseline: 1.1667x; 1.1620x over previous
//
#include <hip/hip_runtime.h>
#include <hip/hip_fp16.h>
#include <math.h>

#define N_NODES 100000
#define N_EDGES 1600000
#define RR      6
#define CIN     8
#define COUT    16
#define EPS     1e-8f

#define NBLK_A  512
#define ABLOCK  1024
#define CHUNK   (N_EDGES / NBLK_A)      // 3125 (exact)
#define NBUCK   391                     // dst >> 8
#define RECCAP  4608                    // per-bucket cap (mean 4096, +8 sigma)
#define QCAP    1536                    // per-quarter cap

// Dynamic LDS layout for partition_kernel (manual offsets, all aligned):
//   spay : uint2[CHUNK*3]     75000 B  @ 0
//   shdr : uint [CHUNK]       12500 B  @ 75000
//   sbkt : ushort[CHUNK]       6250 B  @ 87500
//   cnt/cur/base/gbase : int[NBUCK]x4  @ 93752  (6256 B)
// total 100008 -> request 100032
#define LDS_SPAY   0
#define LDS_SHDR   75000
#define LDS_SBKT   87500
#define LDS_CNT    93752
#define LDS_TOTAL  100032

// float pair -> packed fp16x2 (RNE)
__device__ inline unsigned int pack_f16(float a, float b) {
    __half2 h = __floats2half2_rn(a, b);
    return *(unsigned int*)&h;
}

// ---------------------------------------------------------------------------
// Phase A v3: ALL global accesses streaming/coalesced.
//   pass 1: count buckets (streaming edge read)
//   scan + reserve global runs
//   pass 2: edge-order: read edges (hot) + sten (STREAMING, was random),
//           pack fp16, scatter record into LDS at its sorted position p
//   pass 3: p-order drain LDS -> global (run-coalesced, same addresses
//           as the previous version)
// ---------------------------------------------------------------------------
__global__ __launch_bounds__(ABLOCK)
void partition_kernel(const int* __restrict__ edges,
                      const float* __restrict__ sten,
                      int* __restrict__ gcur,
                      unsigned int* __restrict__ hdr,
                      unsigned int* __restrict__ pay) {
    extern __shared__ char smem[];
    uint2*          spay = (uint2*)(smem + LDS_SPAY);
    unsigned int*   shdr = (unsigned int*)(smem + LDS_SHDR);
    unsigned short* sbkt = (unsigned short*)(smem + LDS_SBKT);
    int* cnt   = (int*)(smem + LDS_CNT);
    int* cur   = cnt + NBUCK;
    int* base  = cur + NBUCK;
    int* gbase = base + NBUCK;

    int tid = threadIdx.x;
    int blk = blockIdx.x;
    int e0 = blk * CHUNK;

    for (int i = tid; i < NBUCK; i += ABLOCK) { cnt[i] = 0; cur[i] = 0; }
    __syncthreads();

    // pass 1: count buckets (coalesced streaming read of edges)
    for (int i = tid; i < CHUNK; i += ABLOCK) {
        int2 ed = ((const int2*)edges)[e0 + i];
        atomicAdd(&cnt[ed.y >> 8], 1);
    }
    __syncthreads();

    // exclusive scan cnt -> base (wave 0)
    if (tid < 64) {
        int lane = tid;
        int off = 0;
        for (int c = 0; c < NBUCK; c += 64) {
            int idx = c + lane;
            int v = (idx < NBUCK) ? cnt[idx] : 0;
            int orig = v;
#pragma unroll
            for (int d = 1; d < 64; d <<= 1) {
                int t = __shfl_up(v, d);
                if (lane >= d) v += t;
            }
            if (idx < NBUCK) base[idx] = off + v - orig;
            off += __shfl(v, 63);
        }
    }
    __syncthreads();

    // reserve global run per bucket
    for (int b = tid; b < NBUCK; b += ABLOCK) {
        int c = cnt[b];
        gbase[b] = (c > 0) ? atomicAdd(&gcur[b], c) : 0;
    }
    __syncthreads();

    // pass 2: edge-order place + stage. edges hot in L1/L2 from pass 1;
    // sten read is a coalesced stream (lane i reads bytes [48i, 48i+48)).
    for (int i = tid; i < CHUNK; i += ABLOCK) {
        int e = e0 + i;
        int2 ed = ((const int2*)edges)[e];
        int b = ed.y >> 8;
        int p = base[b] + atomicAdd(&cur[b], 1);
        sbkt[p] = (unsigned short)b;
        shdr[p] = ((unsigned int)ed.x << 8) | (unsigned int)(ed.y & 255);
        const float4* sp = (const float4*)(sten + (size_t)e * 12);
        float4 s0 = sp[0], s1 = sp[1], s2 = sp[2];
        uint2* dp = spay + p * 3;
        dp[0] = (uint2){ pack_f16(s0.x, s0.y), pack_f16(s0.z, s0.w) };
        dp[1] = (uint2){ pack_f16(s1.x, s1.y), pack_f16(s1.z, s1.w) };
        dp[2] = (uint2){ pack_f16(s2.x, s2.y), pack_f16(s2.z, s2.w) };
    }
    __syncthreads();

    // pass 3: drain in p-order -> sequential run writes (same global
    // addresses/pattern as previous version, sourced from LDS)
    for (int p = tid; p < CHUNK; p += ABLOCK) {
        int b = (int)sbkt[p];
        int rel = p - base[b];
        long long slot = (long long)gbase[b] + rel;
        if (slot < RECCAP) {
            size_t rs = (size_t)b * RECCAP + slot;
            hdr[rs] = shdr[p];
            const uint2* sp = spay + p * 3;
            uint2 w0 = sp[0], w1 = sp[1], w2 = sp[2];
            unsigned int* dp = pay + rs * 6;            // 24B stride, 8B-aligned
            *(uint2*)(dp + 0) = w0;
            *(uint2*)(dp + 2) = w1;
            *(uint2*)(dp + 4) = w2;
        }
    }
}

// ---------------------------------------------------------------------------
// Phase B: 4 blocks per bucket (quarter = 64 nodes). Dense header read ->
// LDS node-sort (packed src|j) -> 64 nodes x 4 lanes, fp16 payload decode
// at consume. (unchanged this round)
// ---------------------------------------------------------------------------
__global__ __launch_bounds__(256, 6)
void bucket_kernel(const float* __restrict__ x,
                   const float* __restrict__ weight,
                   const float* __restrict__ offset,
                   const float* __restrict__ bias,
                   const int* __restrict__ gcur,
                   const unsigned int* __restrict__ hdr,
                   const unsigned int* __restrict__ pay,
                   float* __restrict__ out) {
    __shared__ unsigned int idxs[QCAP];         // 6 KB: (src<<13) | j
    __shared__ int cnt[64], nbase[64], cur2[64];
    __shared__ float fre[RR * CIN * COUT];
    __shared__ float fim[RR * CIN * COUT];
    __shared__ float bsh[COUT];

    int tid = threadIdx.x;
    int b   = blockIdx.x >> 2;
    int q   = blockIdx.x & 3;

    for (int i = tid; i < RR * CIN * COUT; i += 256) {
        int co = i % (CIN * COUT);              // offset is (CIN, COUT)
        float w = weight[i], off = offset[co];
        fre[i] = w * cosf(off);
        fim[i] = w * sinf(off);
    }
    if (tid < COUT) bsh[tid] = bias[tid];
    if (tid < 64) { cnt[tid] = 0; cur2[tid] = 0; }
    __syncthreads();

    int T = gcur[b];
    if (T > RECCAP) T = RECCAP;

    const unsigned int* hslice = hdr + (size_t)b * RECCAP;

    // pass 1: dense, coalesced header read; count this quarter's nodes
    for (int j = tid; j < T; j += 256) {
        unsigned int h = hslice[j];
        int d = (int)(h & 255u);
        if ((d >> 6) == q) atomicAdd(&cnt[d & 63], 1);
    }
    __syncthreads();

    // exclusive scan of 64 counters (wave 0)
    if (tid < 64) {
        int v = cnt[tid];
        int orig = v;
#pragma unroll
        for (int d = 1; d < 64; d <<= 1) {
            int t = __shfl_up(v, d);
            if (tid >= d) v += t;
        }
        nbase[tid] = v - orig;
    }
    __syncthreads();

    // pass 2: re-read headers (L1-hot, 16KB slice); place packed (src<<13)|j
    for (int j = tid; j < T; j += 256) {
        unsigned int h = hslice[j];
        int d = (int)(h & 255u);
        if ((d >> 6) == q) {
            int dl = d & 63;
            int pos = nbase[dl] + atomicAdd(&cur2[dl], 1);
            if (pos < QCAP)
                idxs[pos] = ((h >> 8) << 13) | (unsigned int)j;
        }
    }
    __syncthreads();

    // compute: 64 nodes x 4 lanes (single batch)
    int local = tid >> 2;
    int n = b * 256 + q * 64 + local;
    int l = tid & 3;
    if (n >= N_NODES) return;

    int deg  = cnt[local];
    int base = nbase[local];
    if (base + deg > QCAP) deg = (base < QCAP) ? (QCAP - base) : 0;

    float ar[RR][2] = {};
    float ai[RR][2] = {};

    uint2 p0 = {}, p1 = {}, p2 = {};
    float2 xv = {};
    if (deg > 0) {
        unsigned int pk = idxs[base];
        int j   = (int)(pk & 8191u);
        int src = (int)(pk >> 13);
        const unsigned int* pp = pay + ((size_t)b * RECCAP + j) * 6;
        p0 = *(const uint2*)(pp + 0);
        p1 = *(const uint2*)(pp + 2);
        p2 = *(const uint2*)(pp + 4);
        xv = *(const float2*)(x + (size_t)src * CIN + 2 * l);
    }
    for (int k = 0; k < deg; ++k) {
        uint2 q0 = {}, q1 = {}, q2 = {};
        float2 nx = {};
        if (k + 1 < deg) {
            unsigned int pk = idxs[base + k + 1];
            int j   = (int)(pk & 8191u);
            int src = (int)(pk >> 13);
            const unsigned int* pp = pay + ((size_t)b * RECCAP + j) * 6;
            q0 = *(const uint2*)(pp + 0);
            q1 = *(const uint2*)(pp + 2);
            q2 = *(const uint2*)(pp + 4);
            nx = *(const float2*)(x + (size_t)src * CIN + 2 * l);
        }
        unsigned int wv[6] = {p0.x, p0.y, p1.x, p1.y, p2.x, p2.y};
#pragma unroll
        for (int r = 0; r < RR; ++r) {
            __half2 h = *(__half2*)&wv[r];
            float sre = __half2float(__low2half(h));
            float sim = __half2float(__high2half(h));
            ar[r][0] = fmaf(sre, xv.x, ar[r][0]);
            ar[r][1] = fmaf(sre, xv.y, ar[r][1]);
            ai[r][0] = fmaf(sim, xv.x, ai[r][0]);
            ai[r][1] = fmaf(sim, xv.y, ai[r][1]);
        }
        p0 = q0; p1 = q1; p2 = q2; xv = nx;
    }

    float yr[COUT], yi[COUT];
#pragma unroll
    for (int o = 0; o < COUT; ++o) { yr[o] = 0.f; yi[o] = 0.f; }
#pragma unroll
    for (int r = 0; r < RR; ++r) {
#pragma unroll
        for (int j = 0; j < 2; ++j) {
            int c = 2 * l + j;
            float are = ar[r][j], aim = ai[r][j];
            const float* fr = &fre[(r * CIN + c) * COUT];
            const float* fi = &fim[(r * CIN + c) * COUT];
#pragma unroll
            for (int o = 0; o < COUT; ++o) {
                yr[o] = fmaf(are, fr[o], yr[o]);
                yr[o] = fmaf(-aim, fi[o], yr[o]);
                yi[o] = fmaf(are, fi[o], yi[o]);
                yi[o] = fmaf(aim, fr[o], yi[o]);
            }
        }
    }
#pragma unroll
    for (int o = 0; o < COUT; ++o) {
        yr[o] += __shfl_xor(yr[o], 1);
        yr[o] += __shfl_xor(yr[o], 2);
        yi[o] += __shfl_xor(yi[o], 1);
        yi[o] += __shfl_xor(yi[o], 2);
    }
    float tmp[8];
    int ob = 4 * l;
#pragma unroll
    for (int j = 0; j < 4; ++j) {
        int o = ob + j;
        float re = yr[o], im = yi[o];
        float mag = sqrtf(re * re + im * im);
        float sc = fmaxf(mag + bsh[o], 0.f) / (mag + EPS);
        tmp[2 * j]     = re * sc;
        tmp[2 * j + 1] = im * sc;
    }
    float4* op = (float4*)(out + (size_t)n * 2 * COUT + 8 * l);
    op[0] = ((const float4*)tmp)[0];
    op[1] = ((const float4*)tmp)[1];
}

extern "C" void kernel_launch(void* const* d_in, const int* in_sizes, int n_in,
                              void* d_out, int out_size, void* d_ws, size_t ws_size,
                              hipStream_t stream) {
    const float* x      = (const float*)d_in[0];
    const int*   edges  = (const int*)d_in[1];
    const float* sten   = (const float*)d_in[2];
    const float* weight = (const float*)d_in[3];
    const float* offset = (const float*)d_in[4];
    const float* bias   = (const float*)d_in[5];
    float* out = (float*)d_out;

    // ws: gcur (4 KB) | hdr (NBUCK*RECCAP*4B = 7.2 MB) | pay (NBUCK*RECCAP*24B = 43.2 MB)
    int* gcur = (int*)d_ws;
    unsigned int* hdr = (unsigned int*)((char*)d_ws + 4096);
    unsigned int* pay = hdr + (size_t)NBUCK * RECCAP;

    // >64KB dynamic LDS needs the opt-in attribute (one-time, not a stream op)
    static int lds_inited = 0;
    if (!lds_inited) {
        (void)hipFuncSetAttribute((const void*)partition_kernel,
                                  hipFuncAttributeMaxDynamicSharedMemorySize,
                                  LDS_TOTAL);
        lds_inited = 1;
    }

    (void)hipMemsetAsync(gcur, 0, sizeof(int) * NBUCK, stream);

    partition_kernel<<<NBLK_A, ABLOCK, LDS_TOTAL, stream>>>(edges, sten, gcur, hdr, pay);
    bucket_kernel<<<NBUCK * 4, 256, 0, stream>>>(x, weight, offset, bias,
                                                 gcur, hdr, pay, out);
}